// Round 1
// baseline (506.277 us; speedup 1.0000x reference)
//
#include <hip/hip_runtime.h>
#include <math.h>

static constexpr int NB = 16;              // batches
static constexpr int NC = 16;              // channels (in = out)
static constexpr int HW = 512 * 512;       // spatial elems per plane = 262144
static constexpr int V4 = HW / 4;          // float4 per plane = 65536
static constexpr int THREADS = 256;
static constexpr int BLK_PER_B = 128;      // blocks per batch
static constexpr int ITERS = V4 / (BLK_PER_B * THREADS); // = 2
static constexpr int GRID = NB * BLK_PER_B;              // = 2048
static constexpr float NEG_SLOPE = 0.1f;
static constexpr float EPS = 1e-8f;

// monotone float <-> sortable-uint encoding (handles negatives) for atomicMin/Max
__device__ __forceinline__ unsigned int fenc(float f) {
    unsigned int u = __float_as_uint(f);
    return (u & 0x80000000u) ? ~u : (u | 0x80000000u);
}
__device__ __forceinline__ float fdec(unsigned int u) {
    u = (u & 0x80000000u) ? (u ^ 0x80000000u) : ~u;
    return __uint_as_float(u);
}

__device__ __forceinline__ float leaky(float v) {
    return v >= 0.0f ? v : NEG_SLOPE * v;
}

// PASS 0: conv + leaky, reduce per-(batch,ochannel) min/max into ws (encoded uints)
// PASS 1: recompute conv + leaky (identical FP order), normalize, store
template<int PASS>
__global__ __launch_bounds__(THREADS)
void cc_kernel(const float* __restrict__ x, const float* __restrict__ w,
               const float* __restrict__ bptr, unsigned int* __restrict__ mnmx,
               float* __restrict__ out)
{
    // pass 2 runs blocks in reverse so the tail of x (hottest in L3) is read first
    const int blk = (PASS == 0) ? blockIdx.x : (GRID - 1 - (int)blockIdx.x);
    const int batch = blk >> 7;                 // / BLK_PER_B
    const int chunk = blk & (BLK_PER_B - 1);
    const float* xb = x + (size_t)batch * NC * HW;

    float wr[16];
    #pragma unroll
    for (int i = 0; i < 16; ++i) wr[i] = w[i];
    const float bias = bptr[0];

    __shared__ float smn[16];
    __shared__ float sscale[16];
    float mn[16], mx[16];

    if (PASS == 0) {
        #pragma unroll
        for (int o = 0; o < 16; ++o) { mn[o] = INFINITY; mx[o] = -INFINITY; }
    } else {
        if (threadIdx.x < 16) {
            const float mnv = fdec(mnmx[batch * 16 + threadIdx.x]);
            const float mxv = fdec(mnmx[256 + batch * 16 + threadIdx.x]);
            smn[threadIdx.x] = mnv;
            sscale[threadIdx.x] = 1.0f / (mxv - mnv + EPS);
        }
        __syncthreads();
    }

    #pragma unroll
    for (int it = 0; it < ITERS; ++it) {
        const int p4 = chunk * (THREADS * ITERS) + it * THREADS + (int)threadIdx.x;
        float4 acc[16];
        #pragma unroll
        for (int o = 0; o < 16; ++o) acc[o] = make_float4(bias, bias, bias, bias);
        #pragma unroll
        for (int c = 0; c < 16; ++c) {
            const float4 xv = reinterpret_cast<const float4*>(xb + (size_t)c * HW)[p4];
            #pragma unroll
            for (int o = 0; o < 16; ++o) {
                const float wc = wr[(c - o) & 15];   // circulant: W2[o][c] = w[(c-o)%16]
                acc[o].x = fmaf(wc, xv.x, acc[o].x);
                acc[o].y = fmaf(wc, xv.y, acc[o].y);
                acc[o].z = fmaf(wc, xv.z, acc[o].z);
                acc[o].w = fmaf(wc, xv.w, acc[o].w);
            }
        }
        #pragma unroll
        for (int o = 0; o < 16; ++o) {
            float4 v = acc[o];
            v.x = leaky(v.x); v.y = leaky(v.y); v.z = leaky(v.z); v.w = leaky(v.w);
            if (PASS == 0) {
                mn[o] = fminf(mn[o], fminf(fminf(v.x, v.y), fminf(v.z, v.w)));
                mx[o] = fmaxf(mx[o], fmaxf(fmaxf(v.x, v.y), fmaxf(v.z, v.w)));
            } else {
                const float m = smn[o], s = sscale[o];
                v.x = (v.x - m) * s; v.y = (v.y - m) * s;
                v.z = (v.z - m) * s; v.w = (v.w - m) * s;
                reinterpret_cast<float4*>(out + (size_t)(batch * NC + o) * HW)[p4] = v;
            }
        }
    }

    if (PASS == 0) {
        // 64-lane butterfly reduce per output channel
        #pragma unroll
        for (int o = 0; o < 16; ++o) {
            #pragma unroll
            for (int s = 32; s >= 1; s >>= 1) {
                mn[o] = fminf(mn[o], __shfl_xor(mn[o], s, 64));
                mx[o] = fmaxf(mx[o], __shfl_xor(mx[o], s, 64));
            }
        }
        __shared__ float cmn[4][16], cmx[4][16];
        const int wave = threadIdx.x >> 6;
        const int lane = threadIdx.x & 63;
        if (lane == 0) {
            #pragma unroll
            for (int o = 0; o < 16; ++o) { cmn[wave][o] = mn[o]; cmx[wave][o] = mx[o]; }
        }
        __syncthreads();
        if (threadIdx.x < 16) {
            float v = cmn[0][threadIdx.x];
            #pragma unroll
            for (int wv = 1; wv < 4; ++wv) v = fminf(v, cmn[wv][threadIdx.x]);
            atomicMin(&mnmx[batch * 16 + threadIdx.x], fenc(v));
        } else if (threadIdx.x < 32) {
            const int o = (int)threadIdx.x - 16;
            float v = cmx[0][o];
            #pragma unroll
            for (int wv = 1; wv < 4; ++wv) v = fmaxf(v, cmx[wv][o]);
            atomicMax(&mnmx[256 + batch * 16 + o], fenc(v));
        }
    }
}

extern "C" void kernel_launch(void* const* d_in, const int* in_sizes, int n_in,
                              void* d_out, int out_size, void* d_ws, size_t ws_size,
                              hipStream_t stream) {
    const float* x = (const float*)d_in[0];
    const float* w = (const float*)d_in[1];
    const float* b = (const float*)d_in[2];
    float* out = (float*)d_out;
    unsigned int* mnmx = (unsigned int*)d_ws;   // [0..255]=min(enc), [256..511]=max(enc)

    // ws is re-poisoned to 0xAA before every call: re-init each launch.
    hipMemsetAsync(mnmx, 0xFF, 256 * sizeof(unsigned int), stream);        // min slots = UINT_MAX
    hipMemsetAsync(mnmx + 256, 0x00, 256 * sizeof(unsigned int), stream);  // max slots = 0

    cc_kernel<0><<<GRID, THREADS, 0, stream>>>(x, w, b, mnmx, out);
    cc_kernel<1><<<GRID, THREADS, 0, stream>>>(x, w, b, mnmx, out);
}

// Round 2
// 488.319 us; speedup vs baseline: 1.0368x; 1.0368x over previous
//
#include <hip/hip_runtime.h>
#include <math.h>

static constexpr int NB = 16;              // batches
static constexpr int NC = 16;              // channels (in = out)
static constexpr int HW = 512 * 512;       // spatial elems per plane
static constexpr int V4 = HW / 4;          // float4 per plane = 65536
static constexpr int THREADS = 256;
static constexpr int BLK_PER_B = 128;      // blocks per batch
static constexpr int ITERS = V4 / (BLK_PER_B * THREADS); // = 2
static constexpr int GRID = NB * BLK_PER_B;              // = 2048
static constexpr float NEG_SLOPE = 0.1f;
static constexpr float EPS = 1e-8f;

typedef float f32x4 __attribute__((ext_vector_type(4)));

__device__ __forceinline__ float leaky(float v) {
    return v >= 0.0f ? v : NEG_SLOPE * v;
}

// ---------------------------------------------------------------------------
// PASS 0: conv (raw, bias-seeded, NO leaky — monotone, folded into reduce),
// per-block min/max partials -> ws (plain stores, no init, no atomics).
// partial layout: part[blk*32 + ch]      = block min of raw conv, ch 0..15
//                 part[blk*32 + 16 + ch] = block max
// ---------------------------------------------------------------------------
__global__ __launch_bounds__(THREADS)
void cc_pass0(const float* __restrict__ x, const float* __restrict__ w,
              const float* __restrict__ bptr, float* __restrict__ part)
{
    const int blk = blockIdx.x;
    const int batch = blk >> 7;                 // / BLK_PER_B
    const int chunk = blk & (BLK_PER_B - 1);
    const float* xb = x + (size_t)batch * NC * HW;

    float wr[16];
    #pragma unroll
    for (int i = 0; i < 16; ++i) wr[i] = w[i];
    const float bias = bptr[0];

    float mn[16], mx[16];
    #pragma unroll
    for (int o = 0; o < 16; ++o) { mn[o] = INFINITY; mx[o] = -INFINITY; }

    #pragma unroll
    for (int it = 0; it < ITERS; ++it) {
        const int p4 = chunk * (THREADS * ITERS) + it * THREADS + (int)threadIdx.x;
        float4 acc[16];
        #pragma unroll
        for (int o = 0; o < 16; ++o) acc[o] = make_float4(bias, bias, bias, bias);
        #pragma unroll
        for (int c = 0; c < 16; ++c) {
            const float4 xv = reinterpret_cast<const float4*>(xb + (size_t)c * HW)[p4];
            #pragma unroll
            for (int o = 0; o < 16; ++o) {
                const float wc = wr[(c - o) & 15];   // circulant: W2[o][c] = w[(c-o)%16]
                acc[o].x = fmaf(wc, xv.x, acc[o].x);
                acc[o].y = fmaf(wc, xv.y, acc[o].y);
                acc[o].z = fmaf(wc, xv.z, acc[o].z);
                acc[o].w = fmaf(wc, xv.w, acc[o].w);
            }
        }
        #pragma unroll
        for (int o = 0; o < 16; ++o) {
            const float4 v = acc[o];
            mn[o] = fminf(mn[o], fminf(fminf(v.x, v.y), fminf(v.z, v.w)));
            mx[o] = fmaxf(mx[o], fmaxf(fmaxf(v.x, v.y), fmaxf(v.z, v.w)));
        }
    }

    // 64-lane butterfly per channel
    #pragma unroll
    for (int o = 0; o < 16; ++o) {
        #pragma unroll
        for (int s = 32; s >= 1; s >>= 1) {
            mn[o] = fminf(mn[o], __shfl_xor(mn[o], s, 64));
            mx[o] = fmaxf(mx[o], __shfl_xor(mx[o], s, 64));
        }
    }
    __shared__ float cmn[4][16], cmx[4][16];
    const int wave = threadIdx.x >> 6;
    const int lane = threadIdx.x & 63;
    if (lane == 0) {
        #pragma unroll
        for (int o = 0; o < 16; ++o) { cmn[wave][o] = mn[o]; cmx[wave][o] = mx[o]; }
    }
    __syncthreads();
    if (threadIdx.x < 16) {
        float v = cmn[0][threadIdx.x];
        #pragma unroll
        for (int wv = 1; wv < 4; ++wv) v = fminf(v, cmn[wv][threadIdx.x]);
        part[(size_t)blk * 32 + threadIdx.x] = v;
    } else if (threadIdx.x < 32) {
        const int o = (int)threadIdx.x - 16;
        float v = cmx[0][o];
        #pragma unroll
        for (int wv = 1; wv < 4; ++wv) v = fmaxf(v, cmx[wv][o]);
        part[(size_t)blk * 32 + threadIdx.x] = v;   // slot 16+o = max
    }
}

// ---------------------------------------------------------------------------
// REDUCE: 16 blocks (one per batch), fold 128 chunk-partials -> finals.
// fin[batch*32 + ch]      = leaky(min)
// fin[batch*32 + 16 + ch] = 1/(leaky(max) - leaky(min) + EPS)
// ---------------------------------------------------------------------------
__global__ __launch_bounds__(256)
void cc_reduce(const float* __restrict__ part, float* __restrict__ fin)
{
    const int batch = blockIdx.x;
    const int t = (int)threadIdx.x;
    const int slot = t & 31;          // 0..15 = min[ch], 16..31 = max[ch]
    const int g = t >> 5;             // 8 groups, 16 chunks each
    const bool isMin = slot < 16;
    float v = isMin ? INFINITY : -INFINITY;
    #pragma unroll
    for (int i = 0; i < BLK_PER_B / 8; ++i) {
        const int c = g * (BLK_PER_B / 8) + i;
        const float p = part[((size_t)batch * BLK_PER_B + c) * 32 + slot];
        v = isMin ? fminf(v, p) : fmaxf(v, p);
    }
    __shared__ float red[8][32];
    red[g][slot] = v;
    __syncthreads();
    if (t < 32) {
        float r = red[0][slot];
        #pragma unroll
        for (int i = 1; i < 8; ++i)
            r = isMin ? fminf(r, red[i][slot]) : fmaxf(r, red[i][slot]);
        red[0][slot] = r;
    }
    __syncthreads();
    if (t < 16) {
        const float mnL = leaky(red[0][t]);
        const float mxL = leaky(red[0][16 + t]);
        fin[batch * 32 + t] = mnL;
        fin[batch * 32 + 16 + t] = 1.0f / (mxL - mnL + EPS);
    }
}

// ---------------------------------------------------------------------------
// PASS 1: recompute conv (identical fma chain), leaky, normalize, NT-store.
// Reverse block order so the L3-hottest tail of x is consumed first.
// ---------------------------------------------------------------------------
__global__ __launch_bounds__(THREADS)
void cc_pass1(const float* __restrict__ x, const float* __restrict__ w,
              const float* __restrict__ bptr, const float* __restrict__ fin,
              float* __restrict__ out)
{
    const int blk = GRID - 1 - (int)blockIdx.x;
    const int batch = blk >> 7;
    const int chunk = blk & (BLK_PER_B - 1);
    const float* xb = x + (size_t)batch * NC * HW;

    float wr[16];
    #pragma unroll
    for (int i = 0; i < 16; ++i) wr[i] = w[i];
    const float bias = bptr[0];

    __shared__ float smn[16];
    __shared__ float sscale[16];
    if (threadIdx.x < 16) {
        smn[threadIdx.x] = fin[batch * 32 + threadIdx.x];
    } else if (threadIdx.x < 32) {
        sscale[threadIdx.x - 16] = fin[batch * 32 + threadIdx.x];
    }
    __syncthreads();

    #pragma unroll
    for (int it = 0; it < ITERS; ++it) {
        const int p4 = chunk * (THREADS * ITERS) + it * THREADS + (int)threadIdx.x;
        float4 acc[16];
        #pragma unroll
        for (int o = 0; o < 16; ++o) acc[o] = make_float4(bias, bias, bias, bias);
        #pragma unroll
        for (int c = 0; c < 16; ++c) {
            const float4 xv = reinterpret_cast<const float4*>(xb + (size_t)c * HW)[p4];
            #pragma unroll
            for (int o = 0; o < 16; ++o) {
                const float wc = wr[(c - o) & 15];
                acc[o].x = fmaf(wc, xv.x, acc[o].x);
                acc[o].y = fmaf(wc, xv.y, acc[o].y);
                acc[o].z = fmaf(wc, xv.z, acc[o].z);
                acc[o].w = fmaf(wc, xv.w, acc[o].w);
            }
        }
        #pragma unroll
        for (int o = 0; o < 16; ++o) {
            const float m = smn[o], s = sscale[o];
            f32x4 v;
            v.x = (leaky(acc[o].x) - m) * s;
            v.y = (leaky(acc[o].y) - m) * s;
            v.z = (leaky(acc[o].z) - m) * s;
            v.w = (leaky(acc[o].w) - m) * s;
            f32x4* dst = reinterpret_cast<f32x4*>(out + (size_t)(batch * NC + o) * HW) + p4;
            __builtin_nontemporal_store(v, dst);
        }
    }
}

extern "C" void kernel_launch(void* const* d_in, const int* in_sizes, int n_in,
                              void* d_out, int out_size, void* d_ws, size_t ws_size,
                              hipStream_t stream) {
    const float* x = (const float*)d_in[0];
    const float* w = (const float*)d_in[1];
    const float* b = (const float*)d_in[2];
    float* out = (float*)d_out;
    float* part = (float*)d_ws;                      // 2048*32 floats = 256 KB
    float* fin  = (float*)d_ws + (size_t)GRID * 32;  // 16*32 floats = 2 KB

    cc_pass0<<<GRID, THREADS, 0, stream>>>(x, w, b, part);
    cc_reduce<<<NB, 256, 0, stream>>>(part, fin);
    cc_pass1<<<GRID, THREADS, 0, stream>>>(x, w, b, fin, out);
}